// Round 5
// baseline (366.688 us; speedup 1.0000x reference)
//
#include <hip/hip_runtime.h>
#include <hip/hip_bf16.h>

#define T_SEQ   2048
#define HIDDEN  2880
#define NQ      64
#define NKV     8
#define HD      64
#define QSIZE   4096   // NQ*HD
#define KVSIZE  512    // NKV*HD
#define QKV_N   5120   // QSIZE + 2*KVSIZE
#define WINDOW  128
#define SCALE_F 0.125f // HD^-0.5
// log2(150000)/32
#define ROPE_L2 0.53733241958f

typedef unsigned short u16;
typedef __attribute__((ext_vector_type(8))) short short8;
typedef __attribute__((ext_vector_type(4))) float f32x4;

__device__ __forceinline__ u16 f2bf(float f) {
  __hip_bfloat16 b = __float2bfloat16(f);
  u16 u; __builtin_memcpy(&u, &b, 2); return u;
}

__device__ __forceinline__ void gload16(const u16* g, u16* l) {
  __builtin_amdgcn_global_load_lds(
      (const __attribute__((address_space(1))) void*)g,
      (__attribute__((address_space(3))) void*)l, 16, 0, 0);
}

// ---------------- prep: zero d_out + cast X + transpose w_qkv/w_o ----------------
#define ZERO_BLKS 1440            // 2048*2880/4 float4 / 1024
#define CAST_BLKS 5760            // 2048*2880/4/256
#define TQ_BX 80
#define TQ_BLKS (80 * 45)         // w_qkv: C=5120/64, R=2880/64
#define TO_BX 45
#define TO_BLKS (45 * 64)         // w_o:  C=2880/64, R=4096/64
#define PREP_BLKS (ZERO_BLKS + CAST_BLKS + TQ_BLKS + TO_BLKS)

__global__ void prep_kernel(const float* __restrict__ hidden,
                            const float* __restrict__ w_qkv,
                            const float* __restrict__ w_o,
                            u16* __restrict__ Xb, u16* __restrict__ Wqt,
                            u16* __restrict__ Wot, float* __restrict__ dout) {
  __shared__ float tile[64][65];
  const int b = blockIdx.x, tid = threadIdx.x;
  if (b < ZERO_BLKS) {           // zero d_out (split-K GEMM2 accumulates into it)
    float4 z = {0.f, 0.f, 0.f, 0.f};
    ((float4*)dout)[(size_t)b * 256 + tid] = z;
    return;
  }
  if (b < ZERO_BLKS + CAST_BLKS) {
    size_t i = (size_t)(b - ZERO_BLKS) * 256 + tid;
    float4 v = ((const float4*)hidden)[i];
    ushort4 o;
    o.x = f2bf(v.x); o.y = f2bf(v.y); o.z = f2bf(v.z); o.w = f2bf(v.w);
    ((ushort4*)Xb)[i] = o;
    return;
  }
  const float* in; u16* out; int R, C, bx, by;
  if (b < ZERO_BLKS + CAST_BLKS + TQ_BLKS) {
    int bb = b - ZERO_BLKS - CAST_BLKS; bx = bb % TQ_BX; by = bb / TQ_BX;
    in = w_qkv; out = Wqt; R = HIDDEN; C = QKV_N;
  } else {
    int bb = b - ZERO_BLKS - CAST_BLKS - TQ_BLKS; bx = bb % TO_BX; by = bb / TO_BX;
    in = w_o; out = Wot; R = QSIZE; C = HIDDEN;
  }
  const int r0 = by * 64, c0 = bx * 64;
  const int tx = tid & 15, ty = tid >> 4;      // 16 x 16, float4 per lane
#pragma unroll
  for (int i = 0; i < 4; ++i) {
    float4 v = *(const float4*)(in + (size_t)(r0 + ty + 16 * i) * C + c0 + tx * 4);
    tile[tx * 4 + 0][ty + 16 * i] = v.x;
    tile[tx * 4 + 1][ty + 16 * i] = v.y;
    tile[tx * 4 + 2][ty + 16 * i] = v.z;
    tile[tx * 4 + 3][ty + 16 * i] = v.w;
  }
  __syncthreads();
  const int rr8 = (tid & 7) * 8, cc0 = tid >> 3;   // short8 per lane
#pragma unroll
  for (int p = 0; p < 2; ++p) {
    int cc = cc0 + 32 * p;
    short8 o;
#pragma unroll
    for (int j = 0; j < 8; ++j) o[j] = (short)f2bf(tile[cc][rr8 + j]);
    *(short8*)(out + (size_t)(c0 + cc) * R + r0 + rr8) = o;
  }
}

// ---------------- bf16 MFMA GEMM, 128x128 tile, BK=64, XOR swizzle ----------------
// Single-buffered (R3 structure — dbuf regressed: 64KB LDS halves blocks/CU).
// XCD-band block mapping: block b -> xcd c=b%8 owns N-tiles [c*NYC,(c+1)*NYC).
// Split-K via blockIdx.y (k0 = blockIdx.y*Ksplit); MODE 0 epilogue = f32
// atomic add (exactly deterministic: 2 commuting adds per address, d_out
// pre-zeroed in prep). MODE 1: fused-rope epilogue (q/k roped, v raw).
template <int MODE>
__global__ __launch_bounds__(256)
void gemm_bt_kernel(const u16* __restrict__ A, const u16* __restrict__ B,
                    float* __restrict__ Cout, const int* __restrict__ positions,
                    u16* __restrict__ qb, u16* __restrict__ kb,
                    u16* __restrict__ vb, int Kstride, int NKT, int Ksplit,
                    int Bvalid, int Nout, int ldc, int NX, int NYC, int NY) {
  __shared__ __align__(16) u16 As[128 * 64];
  __shared__ __align__(16) u16 Bs[128 * 64];
  const int bb = blockIdx.x;
  const int xcd = bb & 7, bi = bb >> 3;
  const int ny = xcd * NYC + (bi % NYC);
  const int mx = bi / NYC;
  if (ny >= NY || mx >= NX) return;
  const int m0 = mx * 128, n0 = ny * 128;
  const int k0 = blockIdx.y * Ksplit;

  const int tid = threadIdx.x;
  const int lane = tid & 63, wave = tid >> 6;
  const int quad = lane >> 4, l16 = lane & 15;
  const int wm = wave >> 1, wn = wave & 1;

  const u16* Aptr[4]; const u16* Bptr[4]; u16* Alds[4]; u16* Blds[4];
#pragma unroll
  for (int it = 0; it < 4; ++it) {
    int c = it * 256 + tid;
    int r = c >> 3;
    int lcol = ((c & 7) ^ (r & 7)) * 8;           // XOR swizzle on GLOBAL side
    Aptr[it] = A + (size_t)(m0 + r) * Kstride + k0 + lcol;
    int br = n0 + r; br = br < Bvalid ? br : Bvalid - 1;
    Bptr[it] = B + (size_t)br * Kstride + k0 + lcol;
    Alds[it] = As + c * 8;
    Blds[it] = Bs + c * 8;
  }

  f32x4 acc[4][4] = {};
  const int sw0 = (quad ^ (l16 & 7)) * 8;

  for (int t = 0, kt = 0; t < NKT; ++t, kt += 64) {
#pragma unroll
    for (int it = 0; it < 4; ++it) gload16(Aptr[it] + kt, Alds[it]);
#pragma unroll
    for (int it = 0; it < 4; ++it) gload16(Bptr[it] + kt, Blds[it]);
    asm volatile("s_waitcnt vmcnt(0)" ::: "memory");
    __syncthreads();
#pragma unroll
    for (int kk = 0; kk < 2; ++kk) {
      const int swo = sw0 ^ (kk * 32);
      short8 af[4], bf[4];
#pragma unroll
      for (int i = 0; i < 4; ++i)
        af[i] = *(const short8*)(As + (wm * 64 + i * 16 + l16) * 64 + swo);
#pragma unroll
      for (int j = 0; j < 4; ++j)
        bf[j] = *(const short8*)(Bs + (wn * 64 + j * 16 + l16) * 64 + swo);
#pragma unroll
      for (int i = 0; i < 4; ++i)
#pragma unroll
        for (int j = 0; j < 4; ++j)
          acc[i][j] = __builtin_amdgcn_mfma_f32_16x16x32_bf16(af[i], bf[j], acc[i][j], 0, 0, 0);
    }
    __syncthreads();
  }

  if (MODE == 0) {
#pragma unroll
    for (int i = 0; i < 4; ++i) {
      const int row = m0 + wm * 64 + i * 16 + quad * 4;
#pragma unroll
      for (int j = 0; j < 4; ++j) {
        const int col = n0 + wn * 64 + j * 16 + l16;
        if (col < Nout)
#pragma unroll
          for (int r = 0; r < 4; ++r)
            unsafeAtomicAdd(&Cout[(size_t)(row + r) * ldc + col], acc[i][j][r]);
      }
    }
  } else {
    const int region = (n0 < QSIZE) ? 0 : (n0 < QSIZE + KVSIZE ? 1 : 2);
    if (region <= 1) {
      float invs[2];
#pragma unroll
      for (int j = 0; j < 2; ++j)
        invs[j] = exp2f(-(float)(j * 16 + l16) * ROPE_L2);
#pragma unroll
      for (int i = 0; i < 4; ++i) {
#pragma unroll
        for (int r = 0; r < 4; ++r) {
          const int row = m0 + wm * 64 + i * 16 + quad * 4 + r;
          const float pos = (float)positions[row];
#pragma unroll
          for (int j = 0; j < 2; ++j) {
            float s, c;
            sincosf(pos * invs[j], &s, &c);
            const float x1 = acc[i][j][r], x2 = acc[i][j + 2][r];
            const float o1 = x1 * c - x2 * s, o2 = x2 * c + x1 * s;
            const int col = n0 + wn * 64 + j * 16 + l16;
            if (region == 0) {
              qb[(size_t)row * QSIZE + col] = f2bf(o1);
              qb[(size_t)row * QSIZE + col + 32] = f2bf(o2);
            } else {
              kb[(size_t)row * KVSIZE + col - QSIZE] = f2bf(o1);
              kb[(size_t)row * KVSIZE + col - QSIZE + 32] = f2bf(o2);
            }
          }
        }
      }
    } else {
#pragma unroll
      for (int i = 0; i < 4; ++i) {
        const int row = m0 + wm * 64 + i * 16 + quad * 4;
#pragma unroll
        for (int j = 0; j < 4; ++j) {
          const int col = n0 + wn * 64 + j * 16 + l16 - (QSIZE + KVSIZE);
#pragma unroll
          for (int r = 0; r < 4; ++r)
            vb[(size_t)(row + r) * KVSIZE + col] = f2bf(acc[i][j][r]);
        }
      }
    }
  }
}

// ---------------- windowed attention with sinks ----------------
__global__ __launch_bounds__(256, 2)
void attn_kernel(const u16* __restrict__ qb, const u16* __restrict__ kb,
                 const u16* __restrict__ vb, const float* __restrict__ sinks,
                 u16* __restrict__ attnb) {
  __shared__ __align__(16) u16 Ks[160 * 72];      // 23040 B
  __shared__ __align__(16) u16 Vt[64 * 164];      // 20992 B, V^T [dim][key]
  __shared__ __align__(16) u16 Pb[4 * 16 * 164];  // 20992 B, per-wave P (Vraw first)
  const int qt = blockIdx.x, g = blockIdx.y;
  const int q0 = qt * 32, kstart = q0 - 128;
  const int tid = threadIdx.x;
  const int lane = tid & 63, wave = tid >> 6;
  const int quad = lane >> 4, l16 = lane & 15;

  for (int s = tid; s < 1280; s += 256) {
    int r = s >> 3, c8 = (s & 7) * 8;
    int tg = kstart + r; tg = tg < 0 ? 0 : tg;
    *(short8*)(Ks + r * 72 + c8) =
        *(const short8*)(kb + (size_t)tg * KVSIZE + g * HD + c8);
  }
  {
    const u16* vbase = vb + g * HD;
#pragma unroll
    for (int it = 0; it < 5; ++it) {
      int s = it * 256 + tid;
      int r = s >> 3, c8 = (s & 7) * 8;
      int tg = kstart + r; tg = tg < 0 ? 0 : tg;
      gload16(vbase + (size_t)tg * KVSIZE + c8, Pb + s * 8);
    }
  }
  asm volatile("s_waitcnt vmcnt(0)" ::: "memory");
  __syncthreads();

  short8 bk[10][2];
#pragma unroll
  for (int jf = 0; jf < 10; ++jf)
#pragma unroll
    for (int kk = 0; kk < 2; ++kk)
      bk[jf][kk] = *(const short8*)(Ks + (jf * 16 + l16) * 72 + kk * 32 + quad * 8);

  for (int s = tid; s < 1280; s += 256) {
    int k8 = s >> 6, d = s & 63;
    short8 tmp;
#pragma unroll
    for (int j = 0; j < 8; ++j) tmp[j] = (short)Pb[(k8 * 8 + j) * 64 + d];
    *(short8*)(Vt + d * 164 + k8 * 8) = tmp;
  }
  __syncthreads();

  const int strip = wave & 1, hb = wave >> 1;
  const int qrow0 = q0 + strip * 16;
  u16* Pw = Pb + wave * 16 * 164;
  for (int hh = 0; hh < 4; ++hh) {
    const int h = g * 8 + hb + hh * 2;
    short8 aq[2];
#pragma unroll
    for (int kk = 0; kk < 2; ++kk)
      aq[kk] = *(const short8*)(qb + (size_t)(qrow0 + l16) * QSIZE + h * HD + kk * 32 + quad * 8);
    f32x4 sc[10];
#pragma unroll
    for (int jf = 0; jf < 10; ++jf) {
      f32x4 c = {0.f, 0.f, 0.f, 0.f};
#pragma unroll
      for (int kk = 0; kk < 2; ++kk)
        c = __builtin_amdgcn_mfma_f32_16x16x32_bf16(aq[kk], bk[jf][kk], c, 0, 0, 0);
      sc[jf] = c;
    }

    const float sink = sinks[h];
    float pinv[4];
#pragma unroll
    for (int r = 0; r < 4; ++r) {
      const int qg = qrow0 + quad * 4 + r;
      float mx = -3.0e38f;
#pragma unroll
      for (int jf = 0; jf < 10; ++jf) {
        int kg = kstart + jf * 16 + l16;
        bool valid = (kg >= 0) && (kg <= qg) && (qg - kg < WINDOW);
        float sv = valid ? sc[jf][r] * SCALE_F : -3.0e38f;
        sc[jf][r] = sv;
        mx = fmaxf(mx, sv);
      }
#pragma unroll
      for (int d = 1; d < 16; d <<= 1) mx = fmaxf(mx, __shfl_xor(mx, d, 64));
      mx = fmaxf(mx, sink);
      float sum = 0.f;
#pragma unroll
      for (int jf = 0; jf < 10; ++jf) {
        float e = __expf(sc[jf][r] - mx);
        sc[jf][r] = e;
        sum += e;
      }
#pragma unroll
      for (int d = 1; d < 16; d <<= 1) sum += __shfl_xor(sum, d, 64);
      sum += __expf(sink - mx);
      pinv[r] = 1.0f / sum;
    }

#pragma unroll
    for (int jf = 0; jf < 10; ++jf)
#pragma unroll
      for (int r = 0; r < 4; ++r)
        Pw[(quad * 4 + r) * 164 + jf * 16 + l16] = f2bf(sc[jf][r] * pinv[r]);

    f32x4 o[4] = {};
#pragma unroll
    for (int kk = 0; kk < 5; ++kk) {
      short8 ap = *(const short8*)(Pw + l16 * 164 + kk * 32 + quad * 8);
#pragma unroll
      for (int jf = 0; jf < 4; ++jf) {
        short8 bv = *(const short8*)(Vt + (jf * 16 + l16) * 164 + kk * 32 + quad * 8);
        o[jf] = __builtin_amdgcn_mfma_f32_16x16x32_bf16(ap, bv, o[jf], 0, 0, 0);
      }
    }
#pragma unroll
    for (int jf = 0; jf < 4; ++jf)
#pragma unroll
      for (int r = 0; r < 4; ++r) {
        int qg = qrow0 + quad * 4 + r;
        attnb[(size_t)qg * QSIZE + h * HD + jf * 16 + l16] = f2bf(o[jf][r]);
      }
  }
}

extern "C" void kernel_launch(void* const* d_in, const int* in_sizes, int n_in,
                              void* d_out, int out_size, void* d_ws, size_t ws_size,
                              hipStream_t stream) {
  (void)in_sizes; (void)n_in; (void)out_size; (void)ws_size;
  const int*   positions = (const int*)d_in[0];
  const float* hidden    = (const float*)d_in[1];
  const float* w_qkv     = (const float*)d_in[2];
  const float* w_o       = (const float*)d_in[3];
  const float* sinks     = (const float*)d_in[4];

  char* p = (char*)d_ws;
  u16* Xb    = (u16*)p; p += (size_t)T_SEQ * HIDDEN * 2;
  u16* Wqt   = (u16*)p; p += (size_t)QKV_N * HIDDEN * 2;
  u16* Wot   = (u16*)p; p += (size_t)HIDDEN * QSIZE * 2;
  u16* qb    = (u16*)p; p += (size_t)T_SEQ * QSIZE * 2;
  u16* kb    = (u16*)p; p += (size_t)T_SEQ * KVSIZE * 2;
  u16* vb    = (u16*)p; p += (size_t)T_SEQ * KVSIZE * 2;
  u16* attnb = (u16*)p; p += (size_t)T_SEQ * QSIZE * 2;

  prep_kernel<<<PREP_BLKS, 256, 0, stream>>>(hidden, w_qkv, w_o, Xb, Wqt, Wot,
                                             (float*)d_out);
  // GEMM1: M=2048(NX=16), N=5120(NY=40,NYC=5), K=2880 (NKT=45, no split)
  gemm_bt_kernel<1><<<dim3(16 * 8 * 5, 1), 256, 0, stream>>>(
      Xb, Wqt, nullptr, positions, qb, kb, vb,
      HIDDEN, 45, 0, QKV_N, QKV_N, QKV_N, 16, 5, 40);
  attn_kernel<<<dim3(T_SEQ / 32, NKV), 256, 0, stream>>>(qb, kb, vb, sinks, attnb);
  // GEMM2: M=2048(NX=16), N=2880(NY=23,NYC=3), K=4096 split 2x2048 (NKT=32)
  gemm_bt_kernel<0><<<dim3(16 * 8 * 3, 2), 256, 0, stream>>>(
      attnb, Wot, (float*)d_out, nullptr, nullptr, nullptr, nullptr,
      QSIZE, 32, 2048, HIDDEN, HIDDEN, HIDDEN, 16, 3, 23);
}

// Round 6
// 318.924 us; speedup vs baseline: 1.1498x; 1.1498x over previous
//
#include <hip/hip_runtime.h>
#include <hip/hip_bf16.h>

#define T_SEQ   2048
#define HIDDEN  2880
#define NQ      64
#define NKV     8
#define HD      64
#define QSIZE   4096   // NQ*HD
#define KVSIZE  512    // NKV*HD
#define QKV_N   5120   // QSIZE + 2*KVSIZE
#define WINDOW  128
#define SCALE_F 0.125f // HD^-0.5
// log2(150000)/32
#define ROPE_L2 0.53733241958f

typedef unsigned short u16;
typedef __attribute__((ext_vector_type(8))) short short8;
typedef __attribute__((ext_vector_type(4))) float f32x4;

__device__ __forceinline__ u16 f2bf(float f) {
  __hip_bfloat16 b = __float2bfloat16(f);
  u16 u; __builtin_memcpy(&u, &b, 2); return u;
}

__device__ __forceinline__ void gload16(const u16* g, u16* l) {
  __builtin_amdgcn_global_load_lds(
      (const __attribute__((address_space(1))) void*)g,
      (__attribute__((address_space(3))) void*)l, 16, 0, 0);
}

// ---------------- prep: cast X + transpose w_qkv (w_o transpose is fused into GEMM1) ----------------
#define CAST_BLKS 5760            // 2048*2880/4/256
#define TQ_BX 80
#define TQ_BLKS (80 * 45)         // w_qkv: C=5120/64, R=2880/64
#define PREP_BLKS (CAST_BLKS + TQ_BLKS)

__global__ void prep_kernel(const float* __restrict__ hidden,
                            const float* __restrict__ w_qkv,
                            u16* __restrict__ Xb, u16* __restrict__ Wqt) {
  __shared__ float tile[64][65];
  const int b = blockIdx.x, tid = threadIdx.x;
  if (b < CAST_BLKS) {
    size_t i = (size_t)b * 256 + tid;
    float4 v = ((const float4*)hidden)[i];
    ushort4 o;
    o.x = f2bf(v.x); o.y = f2bf(v.y); o.z = f2bf(v.z); o.w = f2bf(v.w);
    ((ushort4*)Xb)[i] = o;
    return;
  }
  const int bb = b - CAST_BLKS;
  const int bx = bb % TQ_BX, by = bb / TQ_BX;
  const int r0 = by * 64, c0 = bx * 64;
  const int tx = tid & 15, ty = tid >> 4;      // 16 x 16, float4 per lane
#pragma unroll
  for (int i = 0; i < 4; ++i) {
    float4 v = *(const float4*)(w_qkv + (size_t)(r0 + ty + 16 * i) * QKV_N + c0 + tx * 4);
    tile[tx * 4 + 0][ty + 16 * i] = v.x;
    tile[tx * 4 + 1][ty + 16 * i] = v.y;
    tile[tx * 4 + 2][ty + 16 * i] = v.z;
    tile[tx * 4 + 3][ty + 16 * i] = v.w;
  }
  __syncthreads();
  const int rr8 = (tid & 7) * 8, cc0 = tid >> 3;   // short8 per lane
#pragma unroll
  for (int p = 0; p < 2; ++p) {
    int cc = cc0 + 32 * p;
    short8 o;
#pragma unroll
    for (int j = 0; j < 8; ++j) o[j] = (short)f2bf(tile[cc][rr8 + j]);
    *(short8*)(Wqt + (size_t)(c0 + cc) * HIDDEN + r0 + rr8) = o;
  }
}

// ---------------- bf16 MFMA GEMM, 64x128 tile, BK=64, XOR swizzle ----------------
// 2x2 waves of 32x64 each: 32-VGPR acc -> high wave occupancy (GEMM1 5 blk/CU).
// XCD-band mapping: block b -> xcd c=b%8 owns N-tiles [c*NYC,(c+1)*NYC).
// MODE 0: plain f32 store (col-clamped). MODE 1: fused-rope epilogue PLUS
// trailing heterogeneous blocks (bb >= GEMM_BLKS) that transpose+cast w_o
// (overlaps BW work with GEMM latency; LDS unioned).
template <int MODE>
__global__ __launch_bounds__(256)
void gemm_bt_kernel(const u16* __restrict__ A, const u16* __restrict__ B,
                    float* __restrict__ Cout, const int* __restrict__ positions,
                    u16* __restrict__ qb, u16* __restrict__ kb,
                    u16* __restrict__ vb, const float* __restrict__ tin,
                    u16* __restrict__ tout, int Kstride, int NKT,
                    int Bvalid, int Nout, int ldc, int NX, int NYC, int NY,
                    int GEMM_BLKS) {
  __shared__ __align__(16) u16 smem[(64 + 128) * 64];   // 24 KB
  const int tid = threadIdx.x;
  const int bb = blockIdx.x;

  if (MODE == 1 && bb >= GEMM_BLKS) {
    // transpose+cast w_o [4096][2880] f32 -> Wot [2880][4096] bf16
    float (*tile)[65] = (float (*)[65])smem;            // 16.6 KB, fits
    const int bt = bb - GEMM_BLKS;
    const int bx = bt % 45, by = bt / 45;
    const int r0 = by * 64, c0 = bx * 64;
    const int tx = tid & 15, ty = tid >> 4;
#pragma unroll
    for (int i = 0; i < 4; ++i) {
      float4 v = *(const float4*)(tin + (size_t)(r0 + ty + 16 * i) * HIDDEN + c0 + tx * 4);
      tile[tx * 4 + 0][ty + 16 * i] = v.x;
      tile[tx * 4 + 1][ty + 16 * i] = v.y;
      tile[tx * 4 + 2][ty + 16 * i] = v.z;
      tile[tx * 4 + 3][ty + 16 * i] = v.w;
    }
    __syncthreads();
    const int rr8 = (tid & 7) * 8, cc0 = tid >> 3;
#pragma unroll
    for (int p = 0; p < 2; ++p) {
      int cc = cc0 + 32 * p;
      short8 o;
#pragma unroll
      for (int j = 0; j < 8; ++j) o[j] = (short)f2bf(tile[cc][rr8 + j]);
      *(short8*)(tout + (size_t)(c0 + cc) * QSIZE + r0 + rr8) = o;
    }
    return;
  }

  const int xcd = bb & 7, bi = bb >> 3;
  const int ny = xcd * NYC + (bi % NYC);
  const int mx = bi / NYC;
  if (ny >= NY || mx >= NX) return;
  const int m0 = mx * 64, n0 = ny * 128;

  const int lane = tid & 63, wave = tid >> 6;
  const int quad = lane >> 4, l16 = lane & 15;
  const int wm = wave >> 1, wn = wave & 1;   // m-offset wm*32, n-offset wn*64

  u16* As = smem;                 //  64 x 64 (8 KB)
  u16* Bs = smem + 64 * 64;       // 128 x 64 (16 KB)

  const u16* Aptr[2]; const u16* Bptr[4]; u16* Alds[2]; u16* Blds[4];
#pragma unroll
  for (int it = 0; it < 2; ++it) {
    int c = it * 256 + tid;                       // [0,512)
    int r = c >> 3;
    int lcol = ((c & 7) ^ (r & 7)) * 8;           // XOR swizzle on GLOBAL side
    Aptr[it] = A + (size_t)(m0 + r) * Kstride + lcol;
    Alds[it] = As + c * 8;
  }
#pragma unroll
  for (int it = 0; it < 4; ++it) {
    int c = it * 256 + tid;                       // [0,1024)
    int r = c >> 3;
    int lcol = ((c & 7) ^ (r & 7)) * 8;
    int br = n0 + r; br = br < Bvalid ? br : Bvalid - 1;
    Bptr[it] = B + (size_t)br * Kstride + lcol;
    Blds[it] = Bs + c * 8;
  }

  f32x4 acc[2][4] = {};
  const int sw0 = (quad ^ (l16 & 7)) * 8;

  for (int t = 0, kt = 0; t < NKT; ++t, kt += 64) {
#pragma unroll
    for (int it = 0; it < 2; ++it) gload16(Aptr[it] + kt, Alds[it]);
#pragma unroll
    for (int it = 0; it < 4; ++it) gload16(Bptr[it] + kt, Blds[it]);
    asm volatile("s_waitcnt vmcnt(0)" ::: "memory");
    __syncthreads();
#pragma unroll
    for (int kk = 0; kk < 2; ++kk) {
      const int swo = sw0 ^ (kk * 32);
      short8 af[2], bf[4];
#pragma unroll
      for (int i = 0; i < 2; ++i)
        af[i] = *(const short8*)(As + (wm * 32 + i * 16 + l16) * 64 + swo);
#pragma unroll
      for (int j = 0; j < 4; ++j)
        bf[j] = *(const short8*)(Bs + (wn * 64 + j * 16 + l16) * 64 + swo);
#pragma unroll
      for (int i = 0; i < 2; ++i)
#pragma unroll
        for (int j = 0; j < 4; ++j)
          acc[i][j] = __builtin_amdgcn_mfma_f32_16x16x32_bf16(af[i], bf[j], acc[i][j], 0, 0, 0);
    }
    __syncthreads();
  }

  if (MODE == 0) {
#pragma unroll
    for (int i = 0; i < 2; ++i) {
      const int row = m0 + wm * 32 + i * 16 + quad * 4;
#pragma unroll
      for (int j = 0; j < 4; ++j) {
        const int col = n0 + wn * 64 + j * 16 + l16;
        if (col < Nout)
#pragma unroll
          for (int r = 0; r < 4; ++r)
            Cout[(size_t)(row + r) * ldc + col] = acc[i][j][r];
      }
    }
  } else {
    const int region = (n0 < QSIZE) ? 0 : (n0 < QSIZE + KVSIZE ? 1 : 2);
    if (region <= 1) {
      float invs[2];
#pragma unroll
      for (int j = 0; j < 2; ++j)
        invs[j] = exp2f(-(float)(j * 16 + l16) * ROPE_L2);
#pragma unroll
      for (int i = 0; i < 2; ++i) {
#pragma unroll
        for (int r = 0; r < 4; ++r) {
          const int row = m0 + wm * 32 + i * 16 + quad * 4 + r;
          const float pos = (float)positions[row];
#pragma unroll
          for (int j = 0; j < 2; ++j) {
            float s, c;
            sincosf(pos * invs[j], &s, &c);
            const float x1 = acc[i][j][r], x2 = acc[i][j + 2][r];
            const float o1 = x1 * c - x2 * s, o2 = x2 * c + x1 * s;
            const int col = n0 + wn * 64 + j * 16 + l16;
            if (region == 0) {
              qb[(size_t)row * QSIZE + col] = f2bf(o1);
              qb[(size_t)row * QSIZE + col + 32] = f2bf(o2);
            } else {
              kb[(size_t)row * KVSIZE + col - QSIZE] = f2bf(o1);
              kb[(size_t)row * KVSIZE + col - QSIZE + 32] = f2bf(o2);
            }
          }
        }
      }
    } else {
#pragma unroll
      for (int i = 0; i < 2; ++i) {
        const int row = m0 + wm * 32 + i * 16 + quad * 4;
#pragma unroll
        for (int j = 0; j < 4; ++j) {
          const int col = n0 + wn * 64 + j * 16 + l16 - (QSIZE + KVSIZE);
#pragma unroll
          for (int r = 0; r < 4; ++r)
            vb[(size_t)(row + r) * KVSIZE + col] = f2bf(acc[i][j][r]);
        }
      }
    }
  }
}

// ---------------- windowed attention with sinks ----------------
__global__ __launch_bounds__(256, 2)
void attn_kernel(const u16* __restrict__ qb, const u16* __restrict__ kb,
                 const u16* __restrict__ vb, const float* __restrict__ sinks,
                 u16* __restrict__ attnb) {
  __shared__ __align__(16) u16 Ks[160 * 72];      // 23040 B
  __shared__ __align__(16) u16 Vt[64 * 164];      // 20992 B, V^T [dim][key]
  __shared__ __align__(16) u16 Pb[4 * 16 * 164];  // 20992 B, per-wave P (Vraw first)
  const int qt = blockIdx.x, g = blockIdx.y;
  const int q0 = qt * 32, kstart = q0 - 128;
  const int tid = threadIdx.x;
  const int lane = tid & 63, wave = tid >> 6;
  const int quad = lane >> 4, l16 = lane & 15;

  for (int s = tid; s < 1280; s += 256) {
    int r = s >> 3, c8 = (s & 7) * 8;
    int tg = kstart + r; tg = tg < 0 ? 0 : tg;
    *(short8*)(Ks + r * 72 + c8) =
        *(const short8*)(kb + (size_t)tg * KVSIZE + g * HD + c8);
  }
  {
    const u16* vbase = vb + g * HD;
#pragma unroll
    for (int it = 0; it < 5; ++it) {
      int s = it * 256 + tid;
      int r = s >> 3, c8 = (s & 7) * 8;
      int tg = kstart + r; tg = tg < 0 ? 0 : tg;
      gload16(vbase + (size_t)tg * KVSIZE + c8, Pb + s * 8);
    }
  }
  asm volatile("s_waitcnt vmcnt(0)" ::: "memory");
  __syncthreads();

  short8 bk[10][2];
#pragma unroll
  for (int jf = 0; jf < 10; ++jf)
#pragma unroll
    for (int kk = 0; kk < 2; ++kk)
      bk[jf][kk] = *(const short8*)(Ks + (jf * 16 + l16) * 72 + kk * 32 + quad * 8);

  for (int s = tid; s < 1280; s += 256) {
    int k8 = s >> 6, d = s & 63;
    short8 tmp;
#pragma unroll
    for (int j = 0; j < 8; ++j) tmp[j] = (short)Pb[(k8 * 8 + j) * 64 + d];
    *(short8*)(Vt + d * 164 + k8 * 8) = tmp;
  }
  __syncthreads();

  const int strip = wave & 1, hb = wave >> 1;
  const int qrow0 = q0 + strip * 16;
  u16* Pw = Pb + wave * 16 * 164;
  for (int hh = 0; hh < 4; ++hh) {
    const int h = g * 8 + hb + hh * 2;
    short8 aq[2];
#pragma unroll
    for (int kk = 0; kk < 2; ++kk)
      aq[kk] = *(const short8*)(qb + (size_t)(qrow0 + l16) * QSIZE + h * HD + kk * 32 + quad * 8);
    f32x4 sc[10];
#pragma unroll
    for (int jf = 0; jf < 10; ++jf) {
      f32x4 c = {0.f, 0.f, 0.f, 0.f};
#pragma unroll
      for (int kk = 0; kk < 2; ++kk)
        c = __builtin_amdgcn_mfma_f32_16x16x32_bf16(aq[kk], bk[jf][kk], c, 0, 0, 0);
      sc[jf] = c;
    }

    const float sink = sinks[h];
    float pinv[4];
#pragma unroll
    for (int r = 0; r < 4; ++r) {
      const int qg = qrow0 + quad * 4 + r;
      float mx = -3.0e38f;
#pragma unroll
      for (int jf = 0; jf < 10; ++jf) {
        int kg = kstart + jf * 16 + l16;
        bool valid = (kg >= 0) && (kg <= qg) && (qg - kg < WINDOW);
        float sv = valid ? sc[jf][r] * SCALE_F : -3.0e38f;
        sc[jf][r] = sv;
        mx = fmaxf(mx, sv);
      }
#pragma unroll
      for (int d = 1; d < 16; d <<= 1) mx = fmaxf(mx, __shfl_xor(mx, d, 64));
      mx = fmaxf(mx, sink);
      float sum = 0.f;
#pragma unroll
      for (int jf = 0; jf < 10; ++jf) {
        float e = __expf(sc[jf][r] - mx);
        sc[jf][r] = e;
        sum += e;
      }
#pragma unroll
      for (int d = 1; d < 16; d <<= 1) sum += __shfl_xor(sum, d, 64);
      sum += __expf(sink - mx);
      pinv[r] = 1.0f / sum;
    }

#pragma unroll
    for (int jf = 0; jf < 10; ++jf)
#pragma unroll
      for (int r = 0; r < 4; ++r)
        Pw[(quad * 4 + r) * 164 + jf * 16 + l16] = f2bf(sc[jf][r] * pinv[r]);

    f32x4 o[4] = {};
#pragma unroll
    for (int kk = 0; kk < 5; ++kk) {
      short8 ap = *(const short8*)(Pw + l16 * 164 + kk * 32 + quad * 8);
#pragma unroll
      for (int jf = 0; jf < 4; ++jf) {
        short8 bv = *(const short8*)(Vt + (jf * 16 + l16) * 164 + kk * 32 + quad * 8);
        o[jf] = __builtin_amdgcn_mfma_f32_16x16x32_bf16(ap, bv, o[jf], 0, 0, 0);
      }
    }
#pragma unroll
    for (int jf = 0; jf < 4; ++jf)
#pragma unroll
      for (int r = 0; r < 4; ++r) {
        int qg = qrow0 + quad * 4 + r;
        attnb[(size_t)qg * QSIZE + h * HD + jf * 16 + l16] = f2bf(o[jf][r]);
      }
  }
}

extern "C" void kernel_launch(void* const* d_in, const int* in_sizes, int n_in,
                              void* d_out, int out_size, void* d_ws, size_t ws_size,
                              hipStream_t stream) {
  (void)in_sizes; (void)n_in; (void)out_size; (void)ws_size;
  const int*   positions = (const int*)d_in[0];
  const float* hidden    = (const float*)d_in[1];
  const float* w_qkv     = (const float*)d_in[2];
  const float* w_o       = (const float*)d_in[3];
  const float* sinks     = (const float*)d_in[4];

  char* p = (char*)d_ws;
  u16* Xb    = (u16*)p; p += (size_t)T_SEQ * HIDDEN * 2;
  u16* Wqt   = (u16*)p; p += (size_t)QKV_N * HIDDEN * 2;
  u16* Wot   = (u16*)p; p += (size_t)HIDDEN * QSIZE * 2;
  u16* qb    = (u16*)p; p += (size_t)T_SEQ * QSIZE * 2;
  u16* kb    = (u16*)p; p += (size_t)T_SEQ * KVSIZE * 2;
  u16* vb    = (u16*)p; p += (size_t)T_SEQ * KVSIZE * 2;
  u16* attnb = (u16*)p; p += (size_t)T_SEQ * QSIZE * 2;

  prep_kernel<<<PREP_BLKS, 256, 0, stream>>>(hidden, w_qkv, Xb, Wqt);
  // GEMM1: M=2048(NX=32, 64-row tiles), N=5120(NY=40,NYC=5), K=2880(NKT=45)
  // blocks [0,1280) = GEMM; [1280, 1280+2880) = fused w_o transpose
  gemm_bt_kernel<1><<<32 * 8 * 5 + 45 * 64, 256, 0, stream>>>(
      Xb, Wqt, nullptr, positions, qb, kb, vb, w_o, Wot,
      HIDDEN, 45, QKV_N, QKV_N, QKV_N, 32, 5, 40, 32 * 8 * 5);
  attn_kernel<<<dim3(T_SEQ / 32, NKV), 256, 0, stream>>>(qb, kb, vb, sinks, attnb);
  // GEMM2: M=2048(NX=32), N=2880(NY=23,NYC=3), K=4096(NKT=64)
  gemm_bt_kernel<0><<<32 * 8 * 3, 256, 0, stream>>>(
      attnb, Wot, (float*)d_out, nullptr, nullptr, nullptr, nullptr,
      nullptr, nullptr, QSIZE, 64, HIDDEN, HIDDEN, HIDDEN, 32, 3, 23, 32 * 8 * 3);
}